// Round 9
// baseline (532.838 us; speedup 1.0000x reference)
//
#include <hip/hip_runtime.h>

// Problem constants (reference.py)
#define N_ENV 100000
#define DIM   400
#define MPTS  2000
#define NSTR  2000
#define NTRN  100

// GEMM tiling
#define BM 256                   // rows per block: 4 waves x 64 rows, A in registers
#define NPAD 100352              // 392 * 256
#define KPAD 416                 // 13 * 32
#define MPAD 2048                // 16 * 128
#define KTILES 13
#define NBLK (NPAD / BM)         // 392
#define CSTEPS 32                // 32 column steps x 64 cols = 2048
#define CHUNK 64                 // prologue normalize chunk (rows)
#define LDST 424                 // prologue LDS row stride in shorts
#define RINGB 53248              // bytes per cstep B buffer: 52 frags * 1024

typedef __attribute__((ext_vector_type(8))) short short8;
typedef __attribute__((ext_vector_type(4))) float float4v;

#define AS1(p) ((const __attribute__((address_space(1))) void*)(p))
#define AS3(p) ((__attribute__((address_space(3))) void*)(p))

__device__ __forceinline__ unsigned short f2bf(float f) {
  union { float f; unsigned int u; } v; v.f = f;
  unsigned int u = v.u;
  u += 0x7fffu + ((u >> 16) & 1u);   // round-to-nearest-even
  return (unsigned short)(u >> 16);
}
__device__ __forceinline__ float bf2f(unsigned short s) {
  union { unsigned int u; float f; } v; v.u = ((unsigned int)s) << 16;
  return v.f;
}

// ---------------------------------------------------------------------------
// prep: wm[m] = weights[col_seg[m]] (0 in pad region), zero d_out
// ---------------------------------------------------------------------------
__global__ __launch_bounds__(256) void prep_kernel(
    const float* __restrict__ w, const int* __restrict__ col_seg,
    float* __restrict__ wm, float* __restrict__ out) {
  int t = blockIdx.x * 256 + threadIdx.x;
  if (t < MPAD) wm[t] = (t < MPTS) ? w[col_seg[t]] : 0.f;
  if (t < NSTR) out[t] = 0.f;
}

// ---------------------------------------------------------------------------
// B swizzle: fp32 support_points [MPTS,DIM] -> bf16 fragments:
// Bsw[((pn*13+kt)*8+cf)*64+lane][e] =
//   B[pn*128+cf*16+(lane&15)][kt*32+(lane>>4)*8+e]  (0 outside MPTS/DIM)
// One frag = 64 lanes x 16 B = 1 KB, contiguous -> global_load_lds-able.
// ---------------------------------------------------------------------------
__global__ __launch_bounds__(256) void bswz_kernel(
    const float* __restrict__ sp, short8* __restrict__ Bsw) {
  int u = blockIdx.x * 256 + threadIdx.x;     // < 16*13*8*64 = 106496
  int lane = u & 63;
  int v = u >> 6;          // ((pn*13+kt)*8+cf)
  int cf = v & 7;
  int w = v >> 3;          // pn*13+kt
  int kt = w % 13;
  int pn = w / 13;
  int col = pn * 128 + cf * 16 + (lane & 15);
  int kb  = kt * 32 + ((lane >> 4) << 3);
  short8 o = (short8){0, 0, 0, 0, 0, 0, 0, 0};
  if (col < MPTS && kb < DIM) {   // DIM divisible by 8: chunks never straddle
    const float* p = sp + (size_t)col * DIM + kb;
    float4 a = *(const float4*)p;
    float4 b = *(const float4*)(p + 4);
    o[0] = (short)f2bf(a.x); o[1] = (short)f2bf(a.y);
    o[2] = (short)f2bf(a.z); o[3] = (short)f2bf(a.w);
    o[4] = (short)f2bf(b.x); o[5] = (short)f2bf(b.y);
    o[6] = (short)f2bf(b.z); o[7] = (short)f2bf(b.w);
  }
  Bsw[u] = o;
}

// ---------------------------------------------------------------------------
// Round-9 = round-8 resubmitted verbatim (round-8 bench was the same infra
// failure as round-5: "MI355X container failed twice"; round-5's identical
// failure resolved on verbatim resubmit; kernel audit found no hang hazard).
// Round-8 theory recap — raise arithmetic intensity per LDS byte. R6/R7
// identical at 265us: LDS B-reads (8 waves x 52KB = 416 ds_read_b128/CU/
// cstep ~ 4992 cyc on the shared LDS pipe) bound the cstep; rescheduling
// didn't help (compiler already pipelines lgkmcnt). Fix: 4 waves x 64 rows
// (BM unchanged) -> each B frag feeds 4 MFMAs instead of 2: LDS traffic per
// cstep HALVES (208 reads ~2496 cyc), MFMA/SIMD stays 208x19.4 ~4035 cyc ->
// matrix pipe is the long pole.
// af[4][13] = 208 regs is legal here: 106.5KB LDS -> 1 block/CU -> 1 wave/
// SIMD -> 512-reg unified budget (af is AGPR-eligible; MFMA reads A from
// AGPR). No launch_bounds min-waves (R4 lesson: the clamp caused the spills,
// not the array). All af/acc indexing static (kt fully unrolled).
// Watch: WRITE_SIZE ~3MB = no spills; balloons -> revert.
// ---------------------------------------------------------------------------
__global__ __launch_bounds__(256, 1) void gemm_fused_kernel(
    const float* __restrict__ A,        // raw power_spectrum fp32 [N_ENV][DIM]
    const short8* __restrict__ Bsw,     // swizzled B fragments
    const float* __restrict__ wm,       // [MPAD]
    const int* __restrict__ row_seg,    // [N_ENV]
    float* __restrict__ out) {          // [NSTR]
  extern __shared__ unsigned char smem[];          // 2*RINGB = 106496 B
  unsigned short* As = (unsigned short*)smem;      // prologue staging view

  const int tid  = threadIdx.x;
  const int lane = tid & 63;
  const int wid  = tid >> 6;            // 0..3: owns rows [wid*64, wid*64+64)
  const int frow = lane & 15;
  const int koff = (lane >> 4) * 8;
  const long row_base = (long)blockIdx.x * BM;

  short8 af[4][13];                     // 208 regs: this wave's A, resident

  // ---- Prologue: 4 chunks of 64 rows: stage -> normalize -> extract ------
  for (int ch = 0; ch < 4; ++ch) {
    const long rb = row_base + (long)ch * CHUNK;
    int rows_valid = (int)(N_ENV - rb);
    if (rows_valid > CHUNK) rows_valid = CHUNK;
    if (rows_valid < 0) rows_valid = 0;

    // stage: coalesced fp32 -> bf16 -> LDS (nontemporal: A has zero reuse)
    {
      const float4v* Ag = (const float4v*)(A + rb * DIM);
      for (int c = tid; c < CHUNK * (DIM / 4); c += 256) {  // 6400 chunks
        int row = c / 100;                                  // 100 float4/row
        int kc  = c - row * 100;
        uint2 packed = (uint2){0u, 0u};
        if (row < rows_valid) {
          float4v v = __builtin_nontemporal_load(&Ag[c]);
          packed.x = (unsigned int)f2bf(v[0]) | ((unsigned int)f2bf(v[1]) << 16);
          packed.y = (unsigned int)f2bf(v[2]) | ((unsigned int)f2bf(v[3]) << 16);
        }
        *(uint2*)&As[row * LDST + kc * 4] = packed;
      }
      if (tid < CHUNK) {   // zero K-pad [400,424): read by kt=12 fragments
        uint4 z = (uint4){0u, 0u, 0u, 0u};
        uint4* zp = (uint4*)&As[tid * LDST + 400];
        zp[0] = z; zp[1] = z; zp[2] = z;
      }
    }
    __syncthreads();

    // normalize in place: 4 threads per row, 104 shorts each (13 x short8;
    // the q=3 slice covers [312,416): includes the zeroed pad, harmless)
    {
      int row = tid >> 2, q = tid & 3;
      unsigned short* rp = &As[row * LDST + q * 104];
      short8 vals[13];
      float ss = 0.f;
#pragma unroll
      for (int i = 0; i < 13; ++i) {
        vals[i] = *(const short8*)(rp + i * 8);
#pragma unroll
        for (int e = 0; e < 8; ++e) {
          float f = bf2f((unsigned short)vals[i][e]);
          ss += f * f;
        }
      }
      ss += __shfl_xor(ss, 1);
      ss += __shfl_xor(ss, 2);
      float rn = (ss > 0.f) ? rsqrtf(ss) : 0.f;
#pragma unroll
      for (int i = 0; i < 13; ++i) {
        short8 o;
#pragma unroll
        for (int e = 0; e < 8; ++e)
          o[e] = (short)f2bf(bf2f((unsigned short)vals[i][e]) * rn);
        *(short8*)(rp + i * 8) = o;
      }
    }
    __syncthreads();

    // extract: the owning wave pulls its 52 fragments into registers
    if (wid == ch) {
      const unsigned short* Ab = &As[frow * LDST + koff];
#pragma unroll
      for (int i = 0; i < 4; ++i)
#pragma unroll
        for (int kt = 0; kt < 13; ++kt)
          af[i][kt] = *(const short8*)(Ab + i * (16 * LDST) + kt * 32);
    }
    __syncthreads();   // before next chunk (or ring) overwrites LDS
  }

  // ---- Main loop: LDS-ring B pipeline + register A -----------------------
  float vacc[4][4];
#pragma unroll
  for (int i = 0; i < 4; ++i)
#pragma unroll
    for (int r = 0; r < 4; ++r) vacc[i][r] = 0.f;

  // stage cstep s into ring buffer (s&1): 52 frags, spread over 4 waves
#define STAGE_CSTEP(s)                                                        \
  {                                                                           \
    const int pn_ = (s) >> 1, cfb_ = ((s) & 1) * 4;                           \
    unsigned char* buf_ = smem + (size_t)((s) & 1) * RINGB;                   \
    for (int f = wid; f < 52; f += 4) {                                       \
      int kt_ = f >> 2, j_ = f & 3;                                           \
      const short8* src_ =                                                    \
          Bsw + ((((size_t)pn_ * 13 + kt_) * 8) + cfb_ + j_) * 64 + lane;     \
      __builtin_amdgcn_global_load_lds(AS1(src_), AS3(buf_ + f * 1024),       \
                                       16, 0, 0);                             \
    }                                                                         \
  }

  STAGE_CSTEP(0);
  __syncthreads();   // compiler drains vmcnt before s_barrier -> buf0 ready

#pragma unroll 1
  for (int s = 0; s < CSTEPS; ++s) {
    if (s + 1 < CSTEPS) STAGE_CSTEP(s + 1);   // hidden under 13 kt of MFMA

    const unsigned short* buf =
        (const unsigned short*)(smem + (size_t)(s & 1) * RINGB);

    // wmv loads issued early: vmcnt drains under the kt loop
    float wmv[4];
#pragma unroll
    for (int j = 0; j < 4; ++j)
      wmv[j] = wm[s * 64 + j * 16 + frow];

    float4v acc[4][4];
#pragma unroll
    for (int i = 0; i < 4; ++i)
#pragma unroll
      for (int j = 0; j < 4; ++j) acc[i][j] = (float4v){0.f, 0.f, 0.f, 0.f};

#pragma unroll
    for (int kt = 0; kt < KTILES; ++kt) {
      short8 bf[4];
#pragma unroll
      for (int j = 0; j < 4; ++j)
        bf[j] = *(const short8*)(buf + (kt * 4 + j) * 512 + lane * 8);
#pragma unroll
      for (int i = 0; i < 4; ++i)
#pragma unroll
        for (int j = 0; j < 4; ++j)
          acc[i][j] = __builtin_amdgcn_mfma_f32_16x16x32_bf16(
              af[i][kt], bf[j], acc[i][j], 0, 0, 0);
    }

    // epilogue: vacc[row] += wm[col] * C^2 over this step's 4 col-frags
#pragma unroll
    for (int i = 0; i < 4; ++i)
#pragma unroll
      for (int r = 0; r < 4; ++r) {
        float sum = 0.f;
#pragma unroll
        for (int j = 0; j < 4; ++j) {
          float c = acc[i][j][r];
          sum += wmv[j] * c * c;
        }
        vacc[i][r] += sum;
      }

    __syncthreads();   // all waves done reading buf[s&1]; stage(s+1) drained
  }

  // cross-lane reduce over 16-lane groups (same C/D rows), then atomics
#pragma unroll
  for (int i = 0; i < 4; ++i)
#pragma unroll
    for (int r = 0; r < 4; ++r) {
      float s = vacc[i][r];
      s += __shfl_xor(s, 1);
      s += __shfl_xor(s, 2);
      s += __shfl_xor(s, 4);
      s += __shfl_xor(s, 8);
      if ((lane & 15) == 0) {
        long n = row_base + wid * 64 + i * 16 + (lane >> 4) * 4 + r;
        if (n < N_ENV) atomicAdd(&out[row_seg[n]], s);
      }
    }
}

// ---------------------------------------------------------------------------
extern "C" void kernel_launch(void* const* d_in, const int* in_sizes, int n_in,
                              void* d_out, int out_size, void* d_ws, size_t ws_size,
                              hipStream_t stream) {
  const float* ps      = (const float*)d_in[0];  // [N_ENV, DIM]
  const float* sp      = (const float*)d_in[1];  // [MPTS, DIM]
  const float* w       = (const float*)d_in[2];  // [1, NTRN]
  // d_in[3] = all_species: unused by the reference
  const int*   row_seg = (const int*)d_in[4];    // [N_ENV]
  const int*   col_seg = (const int*)d_in[5];    // [MPTS]
  float* out = (float*)d_out;                    // [NSTR]

  char* ws = (char*)d_ws;
  const size_t B_BYTES = (size_t)16 * KTILES * 8 * 64 * 16;  // 1,703,936
  short8* Bsw = (short8*)ws;
  float*  wm  = (float*)(ws + B_BYTES);

  const int LDS_BYTES = 2 * RINGB;   // 106496
  (void)hipFuncSetAttribute((const void*)gemm_fused_kernel,
                            hipFuncAttributeMaxDynamicSharedMemorySize,
                            LDS_BYTES);

  prep_kernel<<<MPAD / 256, 256, 0, stream>>>(w, col_seg, wm, out);
  bswz_kernel<<<(16 * KTILES * 8 * 64) / 256, 256, 0, stream>>>(sp, Bsw);
  gemm_fused_kernel<<<NBLK, 256, LDS_BYTES, stream>>>(ps, Bsw, wm, row_seg, out);
}

// Round 10
// 502.419 us; speedup vs baseline: 1.0605x; 1.0605x over previous
//
#include <hip/hip_runtime.h>

// Problem constants (reference.py)
#define N_ENV 100000
#define DIM   400
#define MPTS  2000
#define NSTR  2000
#define NTRN  100

// GEMM tiling
#define BM 256                   // rows per block: 8 waves x 32 rows, A in registers
#define NPAD 100352              // 392 * 256
#define KPAD 416                 // 13 * 32
#define MPAD 2048                // 16 * 128
#define KTILES 13
#define NBLK (NPAD / BM)         // 392
#define CSTEPS 32                // 32 column steps x 64 cols = 2048
#define CHUNK 64                 // prologue normalize chunk (rows)
#define LDST 424                 // prologue LDS row stride in shorts

typedef __attribute__((ext_vector_type(8))) short short8;
typedef __attribute__((ext_vector_type(4))) short short4v;
typedef __attribute__((ext_vector_type(4))) float float4v;

__device__ __forceinline__ unsigned short f2bf(float f) {
  union { float f; unsigned int u; } v; v.f = f;
  unsigned int u = v.u;
  u += 0x7fffu + ((u >> 16) & 1u);   // round-to-nearest-even
  return (unsigned short)(u >> 16);
}
__device__ __forceinline__ float bf2f(unsigned short s) {
  union { unsigned int u; float f; } v; v.u = ((unsigned int)s) << 16;
  return v.f;
}

// ---------------------------------------------------------------------------
// prep: wm[m] = weights[col_seg[m]] (0 in pad region), zero d_out
// ---------------------------------------------------------------------------
__global__ __launch_bounds__(256) void prep_kernel(
    const float* __restrict__ w, const int* __restrict__ col_seg,
    float* __restrict__ wm, float* __restrict__ out) {
  int t = blockIdx.x * 256 + threadIdx.x;
  if (t < MPAD) wm[t] = (t < MPTS) ? w[col_seg[t]] : 0.f;
  if (t < NSTR) out[t] = 0.f;
}

// ---------------------------------------------------------------------------
// B swizzle: fp32 support_points [MPTS,DIM] -> bf16 fragments:
// Bsw[((pn*13+kt)*8+cf)*64+lane][e] =
//   B[pn*128+cf*16+(lane&15)][kt*32+(lane>>4)*8+e]  (0 outside MPTS/DIM)
// Main-loop bf load = coalesced global_load_dwordx4; all 8 waves of a block
// read the SAME per-kt 4KB window -> L1 dedup.
// ---------------------------------------------------------------------------
__global__ __launch_bounds__(256) void bswz_kernel(
    const float* __restrict__ sp, short8* __restrict__ Bsw) {
  int u = blockIdx.x * 256 + threadIdx.x;     // < 16*13*8*64 = 106496
  int lane = u & 63;
  int v = u >> 6;          // ((pn*13+kt)*8+cf)
  int cf = v & 7;
  int w = v >> 3;          // pn*13+kt
  int kt = w % 13;
  int pn = w / 13;
  int col = pn * 128 + cf * 16 + (lane & 15);
  int kb  = kt * 32 + ((lane >> 4) << 3);
  short8 o = (short8){0, 0, 0, 0, 0, 0, 0, 0};
  if (col < MPTS && kb < DIM) {   // DIM divisible by 8: chunks never straddle
    const float* p = sp + (size_t)col * DIM + kb;
    float4 a = *(const float4*)p;
    float4 b = *(const float4*)(p + 4);
    o[0] = (short)f2bf(a.x); o[1] = (short)f2bf(a.y);
    o[2] = (short)f2bf(a.z); o[3] = (short)f2bf(a.w);
    o[4] = (short)f2bf(b.x); o[5] = (short)f2bf(b.y);
    o[6] = (short)f2bf(b.z); o[7] = (short)f2bf(b.w);
  }
  Bsw[u] = o;
}

// ---------------------------------------------------------------------------
// Round-10: BARRIER-FREE main loop. Evidence: R6 (8w, ring+barrier) 9940
// cyc/cstep; R9 (4w, half LDS traffic) 13390 — TLP dominates LDS traffic,
// and MFMA busy-cycles are constant (~2650): the ~5000 cyc above pipe maxima
// at R6 is the per-cstep 8-wave rendezvous (vmcnt/lgkmcnt drain + MFMA-tail->
// epilogue-tail->barrier serialization). Fix: drop the LDS ring; bf comes
// straight from global Bsw (wave-uniform addresses -> L1 dedups across the 8
// waves; B stays L2-resident since A is nontemporal and only 392 sweeps).
// No __syncthreads after the prologue. 1-kt-deep register prefetch (VMEM
// latency now on the path). LDS shrinks to the 54KB prologue buffer.
// Worst case (no dedup): 416KB/cstep from L2 @56B/cyc = 7.4k cyc < 9.9k.
// ---------------------------------------------------------------------------
__global__ __launch_bounds__(512, 1) void gemm_fused_kernel(
    const float* __restrict__ A,        // raw power_spectrum fp32 [N_ENV][DIM]
    const short8* __restrict__ Bsw,     // swizzled B fragments
    const float* __restrict__ wm,       // [MPAD]
    const int* __restrict__ row_seg,    // [N_ENV]
    float* __restrict__ out) {          // [NSTR]
  __shared__ unsigned short As[CHUNK * LDST];   // 54272 B, prologue only

  const int tid  = threadIdx.x;
  const int lane = tid & 63;
  const int wid  = tid >> 6;            // 0..7: owns rows [wid*32, wid*32+32)
  const int frow = lane & 15;
  const int koff = (lane >> 4) * 8;
  const long row_base = (long)blockIdx.x * BM;

  short8 af[2][13];                     // this wave's A, resident

  // ---- Prologue: 4 chunks of 64 rows: stage -> normalize -> extract ------
  for (int ch = 0; ch < 4; ++ch) {
    const long rb = row_base + (long)ch * CHUNK;
    int rows_valid = (int)(N_ENV - rb);
    if (rows_valid > CHUNK) rows_valid = CHUNK;
    if (rows_valid < 0) rows_valid = 0;

    // stage: coalesced fp32 -> bf16 -> LDS (nontemporal: A has zero reuse,
    // and keeping A out of L2 is what keeps Bsw L2-resident)
    {
      const float4v* Ag = (const float4v*)(A + rb * DIM);
      for (int c = tid; c < CHUNK * (DIM / 4); c += 512) {  // 6400 chunks
        int row = c / 100;                                  // 100 float4/row
        int kc  = c - row * 100;
        uint2 packed = (uint2){0u, 0u};
        if (row < rows_valid) {
          float4v v = __builtin_nontemporal_load(&Ag[c]);
          packed.x = (unsigned int)f2bf(v[0]) | ((unsigned int)f2bf(v[1]) << 16);
          packed.y = (unsigned int)f2bf(v[2]) | ((unsigned int)f2bf(v[3]) << 16);
        }
        *(uint2*)&As[row * LDST + kc * 4] = packed;
      }
      if (tid < CHUNK) {   // zero K-pad [400,424): read by kt=12 fragments
        uint4 z = (uint4){0u, 0u, 0u, 0u};
        uint4* zp = (uint4*)&As[tid * LDST + 400];
        zp[0] = z; zp[1] = z; zp[2] = z;
      }
    }
    __syncthreads();

    // normalize in place: 8 threads per row, 52 shorts each
    {
      int row = tid >> 3, q = tid & 7;
      unsigned short* rp = &As[row * LDST + q * 52];
      short4v vals[13];
      float ss = 0.f;
#pragma unroll
      for (int i = 0; i < 13; ++i) {
        vals[i] = *(const short4v*)(rp + i * 4);
#pragma unroll
        for (int e = 0; e < 4; ++e) {
          float f = bf2f((unsigned short)vals[i][e]);
          ss += f * f;
        }
      }
      ss += __shfl_xor(ss, 1);
      ss += __shfl_xor(ss, 2);
      ss += __shfl_xor(ss, 4);
      float rn = (ss > 0.f) ? rsqrtf(ss) : 0.f;
#pragma unroll
      for (int i = 0; i < 13; ++i) {
        short4v o;
#pragma unroll
        for (int e = 0; e < 4; ++e)
          o[e] = (short)f2bf(bf2f((unsigned short)vals[i][e]) * rn);
        *(short4v*)(rp + i * 4) = o;
      }
    }
    __syncthreads();

    // extract: the two owning waves pull their 26 fragments into registers
    if ((wid >> 1) == ch) {
      const unsigned short* Ab = &As[((wid & 1) * 32 + frow) * LDST + koff];
#pragma unroll
      for (int i = 0; i < 2; ++i)
#pragma unroll
        for (int kt = 0; kt < 13; ++kt)
          af[i][kt] = *(const short8*)(Ab + i * (16 * LDST) + kt * 32);
    }
    __syncthreads();   // before next chunk overwrites LDS
  }

  // ---- Main loop: B direct from global (L1-dedup), NO barriers -----------
  float vacc[2][4];
#pragma unroll
  for (int i = 0; i < 2; ++i)
#pragma unroll
    for (int r = 0; r < 4; ++r) vacc[i][r] = 0.f;

#pragma unroll 1
  for (int s = 0; s < CSTEPS; ++s) {
    const int pn  = s >> 1;
    const int cfb = (s & 1) * 4;
    // frag(kt,j) = Bsw[(pn*104 + kt*8 + cfb + j)*64 + lane]
    const short8* Bc = Bsw + ((size_t)pn * 104 + cfb) * 64 + lane;

    // wmv loads issued early: vmcnt drains under the kt loop
    float wmv[4];
#pragma unroll
    for (int j = 0; j < 4; ++j)
      wmv[j] = wm[s * 64 + j * 16 + frow];

    float4v acc[2][4];
#pragma unroll
    for (int i = 0; i < 2; ++i)
#pragma unroll
      for (int j = 0; j < 4; ++j) acc[i][j] = (float4v){0.f, 0.f, 0.f, 0.f};

    // 1-kt-deep register prefetch: VMEM latency (L1/L2) hides under MFMAs
    short8 bfc[4], bfn[4];
#pragma unroll
    for (int j = 0; j < 4; ++j) bfc[j] = Bc[(size_t)j * 64];

#pragma unroll
    for (int kt = 0; kt < KTILES; ++kt) {
      if (kt + 1 < KTILES) {
#pragma unroll
        for (int j = 0; j < 4; ++j)
          bfn[j] = Bc[(size_t)((kt + 1) * 8 + j) * 64];
      }
#pragma unroll
      for (int i = 0; i < 2; ++i)
#pragma unroll
        for (int j = 0; j < 4; ++j)
          acc[i][j] = __builtin_amdgcn_mfma_f32_16x16x32_bf16(
              af[i][kt], bfc[j], acc[i][j], 0, 0, 0);
      if (kt + 1 < KTILES) {
#pragma unroll
        for (int j = 0; j < 4; ++j) bfc[j] = bfn[j];
      }
    }

    // epilogue: vacc[row] += wm[col] * C^2 over this step's 4 col-frags
#pragma unroll
    for (int i = 0; i < 2; ++i)
#pragma unroll
      for (int r = 0; r < 4; ++r) {
        float sum = 0.f;
#pragma unroll
        for (int j = 0; j < 4; ++j) {
          float c = acc[i][j][r];
          sum += wmv[j] * c * c;
        }
        vacc[i][r] += sum;
      }
  }

  // cross-lane reduce over 16-lane groups (same C/D rows), then atomics
#pragma unroll
  for (int i = 0; i < 2; ++i)
#pragma unroll
    for (int r = 0; r < 4; ++r) {
      float s = vacc[i][r];
      s += __shfl_xor(s, 1);
      s += __shfl_xor(s, 2);
      s += __shfl_xor(s, 4);
      s += __shfl_xor(s, 8);
      if ((lane & 15) == 0) {
        long n = row_base + wid * 32 + i * 16 + (lane >> 4) * 4 + r;
        if (n < N_ENV) atomicAdd(&out[row_seg[n]], s);
      }
    }
}

// ---------------------------------------------------------------------------
extern "C" void kernel_launch(void* const* d_in, const int* in_sizes, int n_in,
                              void* d_out, int out_size, void* d_ws, size_t ws_size,
                              hipStream_t stream) {
  const float* ps      = (const float*)d_in[0];  // [N_ENV, DIM]
  const float* sp      = (const float*)d_in[1];  // [MPTS, DIM]
  const float* w       = (const float*)d_in[2];  // [1, NTRN]
  // d_in[3] = all_species: unused by the reference
  const int*   row_seg = (const int*)d_in[4];    // [N_ENV]
  const int*   col_seg = (const int*)d_in[5];    // [MPTS]
  float* out = (float*)d_out;                    // [NSTR]

  char* ws = (char*)d_ws;
  const size_t B_BYTES = (size_t)16 * KTILES * 8 * 64 * 16;  // 1,703,936
  short8* Bsw = (short8*)ws;
  float*  wm  = (float*)(ws + B_BYTES);

  prep_kernel<<<MPAD / 256, 256, 0, stream>>>(w, col_seg, wm, out);
  bswz_kernel<<<(16 * KTILES * 8 * 64) / 256, 256, 0, stream>>>(sp, Bsw);
  gemm_fused_kernel<<<NBLK, 512, 0, stream>>>(ps, Bsw, wm, row_seg, out);
}